// Round 12
// baseline (101.092 us; speedup 1.0000x reference)
//
#include <hip/hip_runtime.h>
#include <math.h>

#define BT     1024
#define GRID   256
#define NITEMS 4
#define NROW   100
#define DDIM   768
#define EPS_LN 1e-5f
#define EPSF   1e-8f

// LDS layout (bytes), total 160952 <= 163840:
//   u    : [100][384] uint (bf16 pairs; word j <-> cols 2j,2j+1) @ 0 (153600)
//   S    : [768] f32 @ 153600
//   nrm  : [100] f32 @ 156672
//   dens : [100] f32 @ 157072
//   w2   : [100] f32 @ 157472
//   Wsh  : [1]  f32 @ 157872
//   P    : [768] f32 @ 157880   (partial buffer for split column reductions)
#define LDS_BYTES 160952

__device__ __forceinline__ float bflo(unsigned int p) {
    union { unsigned int u; float f; } c; c.u = p << 16; return c.f;
}
__device__ __forceinline__ float bfhi(unsigned int p) {
    union { unsigned int u; float f; } c; c.u = p & 0xFFFF0000u; return c.f;
}
__device__ __forceinline__ unsigned int cvtpk(float lo, float hi) {
    unsigned int r;
    asm("v_cvt_pk_bf16_f32 %0, %1, %2" : "=v"(r) : "v"(lo), "v"(hi));
    return r;
}
__device__ __forceinline__ float wave_sum(float v) {
#pragma unroll
    for (int m = 32; m >= 1; m >>= 1) v += __shfl_xor(v, m, 64);
    return v;
}

// DPP add step: v += dpp_select(v); bound_ctrl=true -> OOB lanes read 0
#define DPPADD(v, ctrl) \
    v += __int_as_float(__builtin_amdgcn_update_dpp(0, __float_as_int(v), ctrl, 0xf, 0xf, true))

// Sum within each 32-lane half via DPP; half-sums land in lanes 31/63.
__device__ __forceinline__ float dpp_half_sum(float v) {
    DPPADD(v, 0x111);   // row_shr:1
    DPPADD(v, 0x112);   // row_shr:2
    DPPADD(v, 0x114);   // row_shr:4
    DPPADD(v, 0x118);   // row_shr:8
    DPPADD(v, 0x142);   // bcast15
    return v;
}
__device__ __forceinline__ float dpp_half_sum_bcast(float v) {
    v = dpp_half_sum(v);
    return __int_as_float(__builtin_amdgcn_ds_swizzle(__float_as_int(v), 0x03E0));
}

extern "C" __global__ void __launch_bounds__(BT, 4)
ccs_kernel(const float* __restrict__ x,
           const float* __restrict__ cc,
           const float* __restrict__ alpha,
           const float* __restrict__ gamma,
           const float* __restrict__ beta,
           const float* __restrict__ thw,
           const float* __restrict__ thb,
           float* __restrict__ out)
{
    extern __shared__ char lds[];
    unsigned int* u   = (unsigned int*)lds;        // [100][384]
    float* S    = (float*)(lds + 153600);
    float* nrm  = (float*)(lds + 156672);
    float* dens = (float*)(lds + 157072);
    float* w2   = (float*)(lds + 157472);
    float* Wsh  = (float*)(lds + 157872);
    float* P    = (float*)(lds + 157880);

    const int tid = threadIdx.x;
    const int w   = tid >> 6;
    const int l   = tid & 63;
    const int li  = l & 31;                  // lane within 32-half
    const int hw  = (w << 1) | (l >> 5);     // half-wave id 0..31
    const int b   = blockIdx.x;
    const int base = 4 * li;

    // extra (4th) rows 96..99 spread across SIMDs: halfwaves 0,10,20,30
    const bool extra = ((hw % 10) == 0) && ((hw / 10) < 4);
    const int  rowX  = 96 + hw / 10;         // valid only when extra

    // ---- hoisted tiny loads (live for whole kernel) ----
    float thwa = 0.f, thwb = 0.f, alphav = 0.f, thbv = 0.f;
    if (w == 0) {
        thwa = thw[l];
        if (l < NROW - 64) thwb = thw[64 + l];
        alphav = alpha[0];
        thbv   = thb[0];
    }

    // ---- gamma/beta for this lane's 24 cols, packed bf16 (24 regs) ----
    uint2 gp6[6], bp6[6];
#pragma unroll
    for (int k = 0; k < 6; ++k) {
        const float4 g4 = *(const float4*)(gamma + 128 * k + base);
        const float4 b4 = *(const float4*)(beta  + 128 * k + base);
        gp6[k].x = cvtpk(g4.x, g4.y); gp6[k].y = cvtpk(g4.z, g4.w);
        bp6[k].x = cvtpk(b4.x, b4.y); bp6[k].y = cvtpk(b4.z, b4.w);
    }

    // LN + L2-normalize one row held in xv (destroys xv), write u/nrm
    auto process_row = [&](float (&xv)[24], int row) {
        float p0 = 0.f, p1 = 0.f;
#pragma unroll
        for (int m = 0; m < 24; ++m) { p0 += xv[m]; p1 = fmaf(xv[m], xv[m], p1); }
        p0 = dpp_half_sum_bcast(p0);
        p1 = dpp_half_sum_bcast(p1);
        const float mu   = p0 * (1.0f / DDIM);
        const float var  = p1 * (1.0f / DDIM) - mu * mu;
        const float A    = rsqrtf(var + EPS_LN);
        const float nmuA = -mu * A;

        float q = 0.f;
#pragma unroll
        for (int k = 0; k < 6; ++k) {
            const float g0 = bflo(gp6[k].x), g1 = bfhi(gp6[k].x);
            const float g2 = bflo(gp6[k].y), g3 = bfhi(gp6[k].y);
            const float b0 = bflo(bp6[k].x), b1 = bfhi(bp6[k].x);
            const float b2 = bflo(bp6[k].y), b3 = bfhi(bp6[k].y);
            float t, v;
            t = fmaf(xv[4*k+0], A, nmuA); v = fmaf(t, g0, b0); xv[4*k+0] = v; q = fmaf(v, v, q);
            t = fmaf(xv[4*k+1], A, nmuA); v = fmaf(t, g1, b1); xv[4*k+1] = v; q = fmaf(v, v, q);
            t = fmaf(xv[4*k+2], A, nmuA); v = fmaf(t, g2, b2); xv[4*k+2] = v; q = fmaf(v, v, q);
            t = fmaf(xv[4*k+3], A, nmuA); v = fmaf(t, g3, b3); xv[4*k+3] = v; q = fmaf(v, v, q);
        }
        q = dpp_half_sum_bcast(q);
        const float qc  = fmaxf(q, 1e-30f);
        const float inv = rsqrtf(qc);
        const float nr  = qc * inv;          // sqrt(q)

        unsigned int* ur = u + row * 384 + 2 * li;
#pragma unroll
        for (int k = 0; k < 6; ++k) {
            uint2 pk;
            pk.x = cvtpk(xv[4 * k + 0] * inv, xv[4 * k + 1] * inv);
            pk.y = cvtpk(xv[4 * k + 2] * inv, xv[4 * k + 3] * inv);
            *(uint2*)&ur[64 * k] = pk;
        }
        if (li == 0) nrm[row] = nr;
    };

    for (int it = 0; it < NITEMS; ++it) {
        const int bi = b + GRID * it;
        const float* xb = x + (size_t)bi * (NROW * DDIM);

        // cc for this item: issue early, consumed in pass 3
        float2 ccv = make_float2(0.f, 0.f);
        if (tid < 384) ccv = *(const float2*)(cc + (size_t)bi * DDIM + 2 * tid);

        // ---------- Pass 1: 3 uniform rows/halfwave + spread extra row ----------
        float xf[24];
        {
            const float* xr = xb + hw * DDIM + base;
#pragma unroll
            for (int k = 0; k < 6; ++k)
                *(float4*)&xf[4 * k] = *(const float4*)(xr + 128 * k);
        }
#pragma unroll
        for (int r = 0; r < 3; ++r) {
            const int row = hw + 32 * r;

            float xn1[24];
            const bool pre = (r < 2) || extra;
            if (pre) {
                const float* xr = (r < 2) ? (xb + (row + 32) * DDIM + base)
                                          : (xb + rowX * DDIM + base);
#pragma unroll
                for (int k = 0; k < 6; ++k)
                    *(float4*)&xn1[4 * k] = *(const float4*)(xr + 128 * k);
            }

            process_row(xf, row);

            if (pre) {
#pragma unroll
                for (int m = 0; m < 24; ++m) xf[m] = xn1[m];
            }
        }
        if (extra) process_row(xf, rowX);
        __syncthreads();

        // ---------- Pass S: S[d] = sum_n u[n][d], split over 2 row-halves ----------
        {
            if (tid < 768) {
                const int h = (tid >= 384) ? 1 : 0;
                const int j = tid - (h ? 384 : 0);
                const unsigned int* up = u + h * 50 * 384 + j;
                float ax = 0.f, ay = 0.f;
#pragma unroll 5
                for (int n = 0; n < 50; ++n) {
                    const unsigned int pw = up[n * 384];
                    ax += bflo(pw); ay += bfhi(pw);
                }
                float* dst = h ? S : P;
                *(float2*)&dst[2 * j] = make_float2(ax, ay);
            }
            __syncthreads();
            if (tid < 384) {
                float2 a = *(float2*)&S[2 * tid];
                const float2 p = *(float2*)&P[2 * tid];
                a.x += p.x; a.y += p.y;
                *(float2*)&S[2 * tid] = a;
            }
        }
        __syncthreads();

        // ---------- Pass 2a: density[n] = u_n . S (half-wave rows, b128 reads, DPP tail) ----------
        {
            float Sv[24];   // this lane's cols: 256k + 8li + j
#pragma unroll
            for (int k = 0; k < 3; ++k) {
                *(float4*)&Sv[8 * k]     = *(const float4*)&S[256 * k + 8 * li];
                *(float4*)&Sv[8 * k + 4] = *(const float4*)&S[256 * k + 8 * li + 4];
            }
#pragma unroll
            for (int r = 0; r < 4; ++r) {
                if (r == 3 && !extra) break;
                const int row = (r < 3) ? (hw + 32 * r) : rowX;
                const unsigned int* ur = u + row * 384 + 4 * li;
                float d = 0.f;
#pragma unroll
                for (int k = 0; k < 3; ++k) {
                    const uint4 pw = *(const uint4*)&ur[128 * k];
                    d = fmaf(bflo(pw.x), Sv[8*k+0], d); d = fmaf(bfhi(pw.x), Sv[8*k+1], d);
                    d = fmaf(bflo(pw.y), Sv[8*k+2], d); d = fmaf(bfhi(pw.y), Sv[8*k+3], d);
                    d = fmaf(bflo(pw.z), Sv[8*k+4], d); d = fmaf(bfhi(pw.z), Sv[8*k+5], d);
                    d = fmaf(bflo(pw.w), Sv[8*k+6], d); d = fmaf(bfhi(pw.w), Sv[8*k+7], d);
                }
                d = dpp_half_sum(d);         // lanes 31/63 hold row sums
                if (li == 31) dens[row] = d;
            }
        }
        __syncthreads();

        // ---------- Pass 2b: min-max normalize, sigmoid threshold, gate (wave 0) ----------
        if (w == 0) {
            const float va = dens[l];
            const bool  hb = (l < NROW - 64);
            const float vb = hb ? dens[64 + l] : 0.f;

            float mxv = hb ? fmaxf(va, vb) : va;
            float mnv = hb ? fminf(va, vb) : va;
#pragma unroll
            for (int m = 32; m >= 1; m >>= 1) {
                mxv = fmaxf(mxv, __shfl_xor(mxv, m, 64));
                mnv = fminf(mnv, __shfl_xor(mnv, m, 64));
            }
            const float rng = 1.0f / (mxv - mnv + EPSF);
            const float ra  = (va - mnv) * rng;
            const float rb  = (vb - mnv) * rng;

            float td = ra * thwa + (hb ? rb * thwb : 0.f);
            td = wave_sum(td);
            const float z  = td + thbv;
            const float th = alphav / (1.0f + expf(-z));

            const float ga  = fmaxf(ra - th, 0.f);
            const float gb_ = hb ? fmaxf(rb - th, 0.f) : 0.f;
            const float sg  = wave_sum(ga + gb_);
            const float wf  = 1.0f / (sg + EPSF);

            w2[l] = ga * wf * nrm[l];
            if (hb) w2[64 + l] = gb_ * wf * nrm[64 + l];
            if (l == 0) Wsh[0] = sg * wf;
        }
        __syncthreads();

        // ---------- Pass 3: shift[d] = sum_n w2[n]u[n][d], split over 2 row-halves ----------
        {
            if (tid < 768) {
                const int h = (tid >= 384) ? 1 : 0;
                const int j = tid - (h ? 384 : 0);
                const unsigned int* up = u + h * 50 * 384 + j;
                const float* wp = w2 + h * 50;
                float ax = 0.f, ay = 0.f;
#pragma unroll 5
                for (int n = 0; n < 50; ++n) {
                    const float wv = wp[n];
                    const unsigned int pw = up[n * 384];
                    ax = fmaf(wv, bflo(pw), ax); ay = fmaf(wv, bfhi(pw), ay);
                }
                float* dst = h ? S : P;      // S is dead after pass 2a
                *(float2*)&dst[2 * j] = make_float2(ax, ay);
            }
            __syncthreads();
            if (tid < 384) {
                const float2 a = *(float2*)&S[2 * tid];
                const float2 p = *(float2*)&P[2 * tid];
                const float W = Wsh[0];
                float2 o;
                o.x = ccv.x + ((a.x + p.x) - ccv.x * W) * (1.0f / NROW);
                o.y = ccv.y + ((a.y + p.y) - ccv.y * W) * (1.0f / NROW);
                *(float2*)(out + (size_t)bi * DDIM + 2 * tid) = o;
            }
        }
        if (it + 1 < NITEMS) __syncthreads();  // protect u/S/P before next item
    }
}

extern "C" void kernel_launch(void* const* d_in, const int* in_sizes, int n_in,
                              void* d_out, int out_size, void* d_ws, size_t ws_size,
                              hipStream_t stream) {
    const float* x     = (const float*)d_in[0];
    const float* cc    = (const float*)d_in[1];
    const float* alpha = (const float*)d_in[2];
    const float* gamma = (const float*)d_in[3];
    const float* beta  = (const float*)d_in[4];
    const float* thw   = (const float*)d_in[5];
    const float* thb   = (const float*)d_in[6];
    float* out = (float*)d_out;

    ccs_kernel<<<GRID, BT, LDS_BYTES, stream>>>(x, cc, alpha, gamma, beta, thw, thb, out);
}

// Round 13
// 86.362 us; speedup vs baseline: 1.1706x; 1.1706x over previous
//
#include <hip/hip_runtime.h>
#include <math.h>

#define BT     1024
#define NROW   100
#define DDIM   768
#define EPS_LN 1e-5f
#define EPSF   1e-8f

// LDS layout (bytes), total 160952 <= 163840:
//   u    : [100][384] uint (bf16 pairs; word j <-> cols 2j,2j+1) @ 0 (153600)
//   S    : [768] f32 @ 153600   (partials: rows 50..99)
//   nrm  : [100] f32 @ 156672
//   dens : [100] f32 @ 157072
//   w2   : [100] f32 @ 157472
//   Wsh  : [1]  f32 @ 157872
//   P    : [768] f32 @ 157880   (partials: rows 0..49)
#define LDS_BYTES 160952

__device__ __forceinline__ float bflo(unsigned int p) {
    union { unsigned int u; float f; } c; c.u = p << 16; return c.f;
}
__device__ __forceinline__ float bfhi(unsigned int p) {
    union { unsigned int u; float f; } c; c.u = p & 0xFFFF0000u; return c.f;
}
__device__ __forceinline__ unsigned int cvtpk(float lo, float hi) {
    unsigned int r;
    asm("v_cvt_pk_bf16_f32 %0, %1, %2" : "=v"(r) : "v"(lo), "v"(hi));
    return r;
}
__device__ __forceinline__ float wave_sum(float v) {
#pragma unroll
    for (int m = 32; m >= 1; m >>= 1) v += __shfl_xor(v, m, 64);
    return v;
}

// DPP add step: v += dpp_select(v); bound_ctrl=true -> OOB lanes read 0
#define DPPADD(v, ctrl) \
    v += __int_as_float(__builtin_amdgcn_update_dpp(0, __float_as_int(v), ctrl, 0xf, 0xf, true))

// Sum within each 32-lane half via DPP; half-sums land in lanes 31/63.
__device__ __forceinline__ float dpp_half_sum(float v) {
    DPPADD(v, 0x111);   // row_shr:1
    DPPADD(v, 0x112);   // row_shr:2
    DPPADD(v, 0x114);   // row_shr:4
    DPPADD(v, 0x118);   // row_shr:8
    DPPADD(v, 0x142);   // bcast15
    return v;
}
__device__ __forceinline__ float dpp_half_sum_bcast(float v) {
    v = dpp_half_sum(v);
    return __int_as_float(__builtin_amdgcn_ds_swizzle(__float_as_int(v), 0x03E0));
}

extern "C" __global__ void __launch_bounds__(BT, 4)
ccs_kernel(const float* __restrict__ x,
           const float* __restrict__ cc,
           const float* __restrict__ alpha,
           const float* __restrict__ gamma,
           const float* __restrict__ beta,
           const float* __restrict__ thw,
           const float* __restrict__ thb,
           float* __restrict__ out)
{
    extern __shared__ char lds[];
    unsigned int* u   = (unsigned int*)lds;        // [100][384]
    float* S    = (float*)(lds + 153600);
    float* nrm  = (float*)(lds + 156672);
    float* dens = (float*)(lds + 157072);
    float* w2   = (float*)(lds + 157472);
    float* Wsh  = (float*)(lds + 157872);
    float* P    = (float*)(lds + 157880);

    const int tid = threadIdx.x;
    const int w   = tid >> 6;
    const int l   = tid & 63;
    const int li  = l & 31;                  // lane within 32-half
    const int hw  = (w << 1) | (l >> 5);     // half-wave id 0..31
    const int b   = blockIdx.x;
    const int base = 4 * li;
    const float* xb = x + (size_t)b * (NROW * DDIM);

    // pass-1 extra (4th) rows 96..99 spread across SIMDs: halfwaves 0,10,20,30
    const bool extra = ((hw % 10) == 0) && ((hw / 10) < 4);
    const int  rowX  = 96 + hw / 10;         // valid only when extra

    // ---- first row's loads issued immediately (critical path) ----
    float xf[24];
    {
        const float* xr = xb + hw * DDIM + base;
#pragma unroll
        for (int k = 0; k < 6; ++k)
            *(float4*)&xf[4 * k] = *(const float4*)(xr + 128 * k);
    }

    // ---- hoisted tiny loads ----
    float thwa = 0.f, thwb = 0.f, alphav = 0.f, thbv = 0.f;
    if (w == 0) {
        thwa = thw[l];
        if (l < NROW - 64) thwb = thw[64 + l];
        alphav = alpha[0];
        thbv   = thb[0];
    }
    float2 ccv = make_float2(0.f, 0.f);
    if (tid < 384) ccv = *(const float2*)(cc + (size_t)b * DDIM + 2 * tid);

    // ---- gamma/beta for this lane's 24 cols, packed bf16 (24 regs) ----
    uint2 gp6[6], bp6[6];
#pragma unroll
    for (int k = 0; k < 6; ++k) {
        const float4 g4 = *(const float4*)(gamma + 128 * k + base);
        const float4 b4 = *(const float4*)(beta  + 128 * k + base);
        gp6[k].x = cvtpk(g4.x, g4.y); gp6[k].y = cvtpk(g4.z, g4.w);
        bp6[k].x = cvtpk(b4.x, b4.y); bp6[k].y = cvtpk(b4.z, b4.w);
    }

    // LN + L2-normalize one row held in xv (destroys xv), write u/nrm
    auto process_row = [&](float (&xv)[24], int row) {
        float p0 = 0.f, p1 = 0.f;
#pragma unroll
        for (int m = 0; m < 24; ++m) { p0 += xv[m]; p1 = fmaf(xv[m], xv[m], p1); }
        p0 = dpp_half_sum_bcast(p0);
        p1 = dpp_half_sum_bcast(p1);
        const float mu   = p0 * (1.0f / DDIM);
        const float var  = p1 * (1.0f / DDIM) - mu * mu;
        const float A    = rsqrtf(var + EPS_LN);
        const float nmuA = -mu * A;

        float q = 0.f;
#pragma unroll
        for (int k = 0; k < 6; ++k) {
            const float g0 = bflo(gp6[k].x), g1 = bfhi(gp6[k].x);
            const float g2 = bflo(gp6[k].y), g3 = bfhi(gp6[k].y);
            const float b0 = bflo(bp6[k].x), b1 = bfhi(bp6[k].x);
            const float b2 = bflo(bp6[k].y), b3 = bfhi(bp6[k].y);
            float t, v;
            t = fmaf(xv[4*k+0], A, nmuA); v = fmaf(t, g0, b0); xv[4*k+0] = v; q = fmaf(v, v, q);
            t = fmaf(xv[4*k+1], A, nmuA); v = fmaf(t, g1, b1); xv[4*k+1] = v; q = fmaf(v, v, q);
            t = fmaf(xv[4*k+2], A, nmuA); v = fmaf(t, g2, b2); xv[4*k+2] = v; q = fmaf(v, v, q);
            t = fmaf(xv[4*k+3], A, nmuA); v = fmaf(t, g3, b3); xv[4*k+3] = v; q = fmaf(v, v, q);
        }
        q = dpp_half_sum_bcast(q);
        const float qc  = fmaxf(q, 1e-30f);
        const float inv = rsqrtf(qc);
        const float nr  = qc * inv;          // sqrt(q)

        unsigned int* ur = u + row * 384 + 2 * li;
#pragma unroll
        for (int k = 0; k < 6; ++k) {
            uint2 pk;
            pk.x = cvtpk(xv[4 * k + 0] * inv, xv[4 * k + 1] * inv);
            pk.y = cvtpk(xv[4 * k + 2] * inv, xv[4 * k + 3] * inv);
            *(uint2*)&ur[64 * k] = pk;
        }
        if (li == 0) nrm[row] = nr;
    };

    // ---------- Pass 1: 3 uniform rows/halfwave + spread extra row ----------
#pragma unroll
    for (int r = 0; r < 3; ++r) {
        const int row = hw + 32 * r;

        float xn1[24];
        const bool pre = (r < 2) || extra;
        if (pre) {
            const float* xr = (r < 2) ? (xb + (row + 32) * DDIM + base)
                                      : (xb + rowX * DDIM + base);
#pragma unroll
            for (int k = 0; k < 6; ++k)
                *(float4*)&xn1[4 * k] = *(const float4*)(xr + 128 * k);
        }

        process_row(xf, row);

        if (pre) {
#pragma unroll
            for (int m = 0; m < 24; ++m) xf[m] = xn1[m];
        }
    }
    if (extra) process_row(xf, rowX);
    __syncthreads();

    // ---------- Pass S: column partials via ds_read_b64 (384 threads, 2 row-halves) ----------
    // thread = (h, j2): h row-half, j2 word-pair [0,192); partial cols 4j2..4j2+3
    if (tid < 384) {
        const int h  = (tid >= 192) ? 1 : 0;
        const int j2 = tid - 192 * h;
        const unsigned int* up = u + (h * 50) * 384 + 2 * j2;
        float a0 = 0.f, a1 = 0.f, a2 = 0.f, a3 = 0.f;
#pragma unroll 5
        for (int n = 0; n < 50; ++n) {
            const uint2 pw = *(const uint2*)&up[n * 384];
            a0 += bflo(pw.x); a1 += bfhi(pw.x);
            a2 += bflo(pw.y); a3 += bfhi(pw.y);
        }
        float* dst = h ? S : P;
        *(float4*)&dst[4 * j2] = make_float4(a0, a1, a2, a3);
    }
    __syncthreads();

    // ---------- Pass 2a: density[n] = u_n . (S+P), FULL-WAVE rows ----------
    {
        // lane l covers words 4l..4l+3 (cols 8l..8l+7) and words 256+2l..+1 (cols 512+4l..+3)
        float Sv[12];
        {
            const float4 sa = *(const float4*)&S[8 * l];
            const float4 pa = *(const float4*)&P[8 * l];
            const float4 sb = *(const float4*)&S[8 * l + 4];
            const float4 pb = *(const float4*)&P[8 * l + 4];
            const float4 sc = *(const float4*)&S[512 + 4 * l];
            const float4 pc = *(const float4*)&P[512 + 4 * l];
            Sv[0] = sa.x + pa.x; Sv[1] = sa.y + pa.y; Sv[2] = sa.z + pa.z; Sv[3] = sa.w + pa.w;
            Sv[4] = sb.x + pb.x; Sv[5] = sb.y + pb.y; Sv[6] = sb.z + pb.z; Sv[7] = sb.w + pb.w;
            Sv[8] = sc.x + pc.x; Sv[9] = sc.y + pc.y; Sv[10] = sc.z + pc.z; Sv[11] = sc.w + pc.w;
        }
        const bool extra2 = ((w % 5) == 0);          // waves 0,5,10,15 take rows 96..99
        const int  rowY   = 96 + w / 5;
#pragma unroll
        for (int r = 0; r < 7; ++r) {
            if (r == 6 && !extra2) break;
            const int row = (r < 6) ? (w + 16 * r) : rowY;
            const unsigned int* ur = u + row * 384;
            const uint4 pw = *(const uint4*)&ur[4 * l];
            const uint2 qw = *(const uint2*)&ur[256 + 2 * l];
            float d = 0.f;
            d = fmaf(bflo(pw.x), Sv[0], d); d = fmaf(bfhi(pw.x), Sv[1], d);
            d = fmaf(bflo(pw.y), Sv[2], d); d = fmaf(bfhi(pw.y), Sv[3], d);
            d = fmaf(bflo(pw.z), Sv[4], d); d = fmaf(bfhi(pw.z), Sv[5], d);
            d = fmaf(bflo(pw.w), Sv[6], d); d = fmaf(bfhi(pw.w), Sv[7], d);
            d = fmaf(bflo(qw.x), Sv[8], d); d = fmaf(bfhi(qw.x), Sv[9], d);
            d = fmaf(bflo(qw.y), Sv[10], d); d = fmaf(bfhi(qw.y), Sv[11], d);
            d = dpp_half_sum(d);
            d += __shfl_xor(d, 32, 64);              // lane 63 holds full row sum
            if (l == 63) dens[row] = d;
        }
    }
    __syncthreads();

    // ---------- Pass 2b: min-max normalize, sigmoid threshold, gate (wave 0) ----------
    if (w == 0) {
        const float va = dens[l];
        const bool  hb = (l < NROW - 64);
        const float vb = hb ? dens[64 + l] : 0.f;

        float mxv = hb ? fmaxf(va, vb) : va;
        float mnv = hb ? fminf(va, vb) : va;
#pragma unroll
        for (int m = 32; m >= 1; m >>= 1) {
            mxv = fmaxf(mxv, __shfl_xor(mxv, m, 64));
            mnv = fminf(mnv, __shfl_xor(mnv, m, 64));
        }
        const float rng = 1.0f / (mxv - mnv + EPSF);
        const float ra  = (va - mnv) * rng;
        const float rb  = (vb - mnv) * rng;

        float td = ra * thwa + (hb ? rb * thwb : 0.f);
        td = wave_sum(td);
        const float z  = td + thbv;
        const float th = alphav / (1.0f + expf(-z));

        const float ga  = fmaxf(ra - th, 0.f);
        const float gb_ = hb ? fmaxf(rb - th, 0.f) : 0.f;
        const float sg  = wave_sum(ga + gb_);
        const float wf  = 1.0f / (sg + EPSF);

        w2[l] = ga * wf * nrm[l];
        if (hb) w2[64 + l] = gb_ * wf * nrm[64 + l];
        if (l == 0) Wsh[0] = sg * wf;
    }
    __syncthreads();

    // ---------- Pass 3: shift partials via ds_read_b64 (384 threads, 2 row-halves) ----------
    if (tid < 384) {
        const int h  = (tid >= 192) ? 1 : 0;
        const int j2 = tid - 192 * h;
        const unsigned int* up = u + (h * 50) * 384 + 2 * j2;
        const float* wp = w2 + h * 50;
        float a0 = 0.f, a1 = 0.f, a2 = 0.f, a3 = 0.f;
#pragma unroll 5
        for (int n = 0; n < 50; ++n) {
            const float wv = wp[n];
            const uint2 pw = *(const uint2*)&up[n * 384];
            a0 = fmaf(wv, bflo(pw.x), a0); a1 = fmaf(wv, bfhi(pw.x), a1);
            a2 = fmaf(wv, bflo(pw.y), a2); a3 = fmaf(wv, bfhi(pw.y), a3);
        }
        float* dst = h ? S : P;              // S/P free again after pass 2a
        *(float4*)&dst[4 * j2] = make_float4(a0, a1, a2, a3);
    }
    __syncthreads();

    // ---------- Output: out[d] = cc + ((S+P)[d] - cc*W)/N ----------
    if (tid < 384) {
        const float2 a = *(float2*)&S[2 * tid];
        const float2 p = *(float2*)&P[2 * tid];
        const float W = Wsh[0];
        float2 o;
        o.x = ccv.x + ((a.x + p.x) - ccv.x * W) * (1.0f / NROW);
        o.y = ccv.y + ((a.y + p.y) - ccv.y * W) * (1.0f / NROW);
        *(float2*)(out + (size_t)b * DDIM + 2 * tid) = o;
    }
}

extern "C" void kernel_launch(void* const* d_in, const int* in_sizes, int n_in,
                              void* d_out, int out_size, void* d_ws, size_t ws_size,
                              hipStream_t stream) {
    const float* x     = (const float*)d_in[0];
    const float* cc    = (const float*)d_in[1];
    const float* alpha = (const float*)d_in[2];
    const float* gamma = (const float*)d_in[3];
    const float* beta  = (const float*)d_in[4];
    const float* thw   = (const float*)d_in[5];
    const float* thb   = (const float*)d_in[6];
    float* out = (float*)d_out;

    ccs_kernel<<<1024, BT, LDS_BYTES, stream>>>(x, cc, alpha, gamma, beta, thw, thb, out);
}

// Round 14
// 77.113 us; speedup vs baseline: 1.3110x; 1.1199x over previous
//
#include <hip/hip_runtime.h>
#include <math.h>

#define BT     1024
#define NROW   100
#define DDIM   768
#define EPS_LN 1e-5f
#define EPSF   1e-8f

// LDS layout (bytes), total 160952 <= 163840:
//   u    : [100][384] uint (bf16 pairs; word j <-> cols 2j,2j+1) @ 0 (153600)
//   S    : [768] f32 @ 153600
//   nrm  : [100] f32 @ 156672
//   dens : [100] f32 @ 157072
//   w2   : [100] f32 @ 157472
//   Wsh  : [1]  f32 @ 157872
//   P    : [768] f32 @ 157880   (partial buffer for split column reductions)
#define LDS_BYTES 160952

__device__ __forceinline__ float bflo(unsigned int p) {
    union { unsigned int u; float f; } c; c.u = p << 16; return c.f;
}
__device__ __forceinline__ float bfhi(unsigned int p) {
    union { unsigned int u; float f; } c; c.u = p & 0xFFFF0000u; return c.f;
}
__device__ __forceinline__ unsigned int cvtpk(float lo, float hi) {
    unsigned int r;
    asm("v_cvt_pk_bf16_f32 %0, %1, %2" : "=v"(r) : "v"(lo), "v"(hi));
    return r;
}
__device__ __forceinline__ float wave_sum(float v) {
#pragma unroll
    for (int m = 32; m >= 1; m >>= 1) v += __shfl_xor(v, m, 64);
    return v;
}

// DPP add step: v += dpp_select(v); bound_ctrl=true -> OOB lanes read 0
#define DPPADD(v, ctrl) \
    v += __int_as_float(__builtin_amdgcn_update_dpp(0, __float_as_int(v), ctrl, 0xf, 0xf, true))

// Sum within each 32-lane half via DPP; half-sums land in lanes 31/63.
__device__ __forceinline__ float dpp_half_sum(float v) {
    DPPADD(v, 0x111);   // row_shr:1
    DPPADD(v, 0x112);   // row_shr:2
    DPPADD(v, 0x114);   // row_shr:4
    DPPADD(v, 0x118);   // row_shr:8
    DPPADD(v, 0x142);   // bcast15
    return v;
}
__device__ __forceinline__ float dpp_half_sum_bcast(float v) {
    v = dpp_half_sum(v);
    return __int_as_float(__builtin_amdgcn_ds_swizzle(__float_as_int(v), 0x03E0));
}

extern "C" __global__ void __launch_bounds__(BT, 4)
ccs_kernel(const float* __restrict__ x,
           const float* __restrict__ cc,
           const float* __restrict__ alpha,
           const float* __restrict__ gamma,
           const float* __restrict__ beta,
           const float* __restrict__ thw,
           const float* __restrict__ thb,
           float* __restrict__ out)
{
    extern __shared__ char lds[];
    unsigned int* u   = (unsigned int*)lds;        // [100][384]
    float* S    = (float*)(lds + 153600);
    float* nrm  = (float*)(lds + 156672);
    float* dens = (float*)(lds + 157072);
    float* w2   = (float*)(lds + 157472);
    float* Wsh  = (float*)(lds + 157872);
    float* P    = (float*)(lds + 157880);

    const int tid = threadIdx.x;
    const int w   = tid >> 6;
    const int l   = tid & 63;
    const int li  = l & 31;                  // lane within 32-half
    const int hw  = (w << 1) | (l >> 5);     // half-wave id 0..31
    const int b   = blockIdx.x;
    const int base = 4 * li;
    const float* xb = x + (size_t)b * (NROW * DDIM);

    // extra (4th) rows 96..99 spread across SIMDs: halfwaves 0,10,20,30
    const bool extra = ((hw % 10) == 0) && ((hw / 10) < 4);
    const int  rowX  = 96 + hw / 10;         // valid only when extra

    // ---- first row's loads issued immediately (critical path) ----
    float xf[24];
    {
        const float* xr = xb + hw * DDIM + base;
#pragma unroll
        for (int k = 0; k < 6; ++k)
            *(float4*)&xf[4 * k] = *(const float4*)(xr + 128 * k);
    }

    // ---- hoisted tiny loads ----
    float thwa = 0.f, thwb = 0.f, alphav = 0.f, thbv = 0.f;
    if (w == 0) {
        thwa = thw[l];
        if (l < NROW - 64) thwb = thw[64 + l];
        alphav = alpha[0];
        thbv   = thb[0];
    }
    float2 ccv = make_float2(0.f, 0.f);
    if (tid < 384) ccv = *(const float2*)(cc + (size_t)b * DDIM + 2 * tid);

    // ---- gamma/beta for this lane's 24 cols, packed bf16 (24 regs) ----
    uint2 gp6[6], bp6[6];
#pragma unroll
    for (int k = 0; k < 6; ++k) {
        const float4 g4 = *(const float4*)(gamma + 128 * k + base);
        const float4 b4 = *(const float4*)(beta  + 128 * k + base);
        gp6[k].x = cvtpk(g4.x, g4.y); gp6[k].y = cvtpk(g4.z, g4.w);
        bp6[k].x = cvtpk(b4.x, b4.y); bp6[k].y = cvtpk(b4.z, b4.w);
    }

    // LN + L2-normalize one row held in xv (destroys xv), write u/nrm
    auto process_row = [&](float (&xv)[24], int row) {
        float p0 = 0.f, p1 = 0.f;
#pragma unroll
        for (int m = 0; m < 24; ++m) { p0 += xv[m]; p1 = fmaf(xv[m], xv[m], p1); }
        p0 = dpp_half_sum_bcast(p0);
        p1 = dpp_half_sum_bcast(p1);
        const float mu   = p0 * (1.0f / DDIM);
        const float var  = p1 * (1.0f / DDIM) - mu * mu;
        const float A    = rsqrtf(var + EPS_LN);
        const float nmuA = -mu * A;

        float q = 0.f;
#pragma unroll
        for (int k = 0; k < 6; ++k) {
            const float g0 = bflo(gp6[k].x), g1 = bfhi(gp6[k].x);
            const float g2 = bflo(gp6[k].y), g3 = bfhi(gp6[k].y);
            const float b0 = bflo(bp6[k].x), b1 = bfhi(bp6[k].x);
            const float b2 = bflo(bp6[k].y), b3 = bfhi(bp6[k].y);
            float t, v;
            t = fmaf(xv[4*k+0], A, nmuA); v = fmaf(t, g0, b0); xv[4*k+0] = v; q = fmaf(v, v, q);
            t = fmaf(xv[4*k+1], A, nmuA); v = fmaf(t, g1, b1); xv[4*k+1] = v; q = fmaf(v, v, q);
            t = fmaf(xv[4*k+2], A, nmuA); v = fmaf(t, g2, b2); xv[4*k+2] = v; q = fmaf(v, v, q);
            t = fmaf(xv[4*k+3], A, nmuA); v = fmaf(t, g3, b3); xv[4*k+3] = v; q = fmaf(v, v, q);
        }
        q = dpp_half_sum_bcast(q);
        const float qc  = fmaxf(q, 1e-30f);
        const float inv = rsqrtf(qc);
        const float nr  = qc * inv;          // sqrt(q)

        unsigned int* ur = u + row * 384 + 2 * li;
#pragma unroll
        for (int k = 0; k < 6; ++k) {
            uint2 pk;
            pk.x = cvtpk(xv[4 * k + 0] * inv, xv[4 * k + 1] * inv);
            pk.y = cvtpk(xv[4 * k + 2] * inv, xv[4 * k + 3] * inv);
            *(uint2*)&ur[64 * k] = pk;
        }
        if (li == 0) nrm[row] = nr;
    };

    // ---------- Pass 1: 3 uniform rows/halfwave + spread extra row ----------
#pragma unroll
    for (int r = 0; r < 3; ++r) {
        const int row = hw + 32 * r;

        float xn1[24];
        const bool pre = (r < 2) || extra;
        if (pre) {
            const float* xr = (r < 2) ? (xb + (row + 32) * DDIM + base)
                                      : (xb + rowX * DDIM + base);
#pragma unroll
            for (int k = 0; k < 6; ++k)
                *(float4*)&xn1[4 * k] = *(const float4*)(xr + 128 * k);
        }

        process_row(xf, row);

        if (pre) {
#pragma unroll
            for (int m = 0; m < 24; ++m) xf[m] = xn1[m];
        }
    }
    if (extra) process_row(xf, rowX);
    __syncthreads();

    // ---------- Pass S: S[d] = sum_n u[n][d], split over 2 row-halves,
    //            even/odd dual accumulation chains for ILP ----------
    {
        if (tid < 768) {
            const int h = (tid >= 384) ? 1 : 0;
            const int j = tid - (h ? 384 : 0);
            const unsigned int* up = u + h * 50 * 384 + j;
            float ax0 = 0.f, ay0 = 0.f, ax1 = 0.f, ay1 = 0.f;
#pragma unroll 5
            for (int n = 0; n < 50; n += 2) {
                const unsigned int pw0 = up[n * 384];
                const unsigned int pw1 = up[(n + 1) * 384];
                ax0 += bflo(pw0); ay0 += bfhi(pw0);
                ax1 += bflo(pw1); ay1 += bfhi(pw1);
            }
            float* dst = h ? S : P;
            *(float2*)&dst[2 * j] = make_float2(ax0 + ax1, ay0 + ay1);
        }
        __syncthreads();
        if (tid < 384) {
            float2 a = *(float2*)&S[2 * tid];
            const float2 p = *(float2*)&P[2 * tid];
            a.x += p.x; a.y += p.y;
            *(float2*)&S[2 * tid] = a;
        }
    }
    __syncthreads();

    // ---------- Pass 2a: density[n] = u_n . S (half-wave rows, b128 reads, DPP tail) ----------
    {
        float Sv[24];   // this lane's cols: 256k + 8li + j
#pragma unroll
        for (int k = 0; k < 3; ++k) {
            *(float4*)&Sv[8 * k]     = *(const float4*)&S[256 * k + 8 * li];
            *(float4*)&Sv[8 * k + 4] = *(const float4*)&S[256 * k + 8 * li + 4];
        }
        auto dens_row = [&](int row) {
            const unsigned int* ur = u + row * 384 + 4 * li;
            float d = 0.f;
#pragma unroll
            for (int k = 0; k < 3; ++k) {
                const uint4 pw = *(const uint4*)&ur[128 * k];
                d = fmaf(bflo(pw.x), Sv[8*k+0], d); d = fmaf(bfhi(pw.x), Sv[8*k+1], d);
                d = fmaf(bflo(pw.y), Sv[8*k+2], d); d = fmaf(bfhi(pw.y), Sv[8*k+3], d);
                d = fmaf(bflo(pw.z), Sv[8*k+4], d); d = fmaf(bfhi(pw.z), Sv[8*k+5], d);
                d = fmaf(bflo(pw.w), Sv[8*k+6], d); d = fmaf(bfhi(pw.w), Sv[8*k+7], d);
            }
            d = dpp_half_sum(d);             // lanes 31/63 hold row sums
            if (li == 31) dens[row] = d;
        };
#pragma unroll
        for (int r = 0; r < 3; ++r) dens_row(hw + 32 * r);
        if (extra) dens_row(rowX);
    }
    __syncthreads();

    // ---------- Pass 2b: min-max normalize, sigmoid threshold, gate (wave 0) ----------
    if (w == 0) {
        const float va = dens[l];
        const bool  hb = (l < NROW - 64);
        const float vb = hb ? dens[64 + l] : 0.f;

        float mxv = hb ? fmaxf(va, vb) : va;
        float mnv = hb ? fminf(va, vb) : va;
#pragma unroll
        for (int m = 32; m >= 1; m >>= 1) {
            mxv = fmaxf(mxv, __shfl_xor(mxv, m, 64));
            mnv = fminf(mnv, __shfl_xor(mnv, m, 64));
        }
        const float rng = 1.0f / (mxv - mnv + EPSF);
        const float ra  = (va - mnv) * rng;
        const float rb  = (vb - mnv) * rng;

        float td = ra * thwa + (hb ? rb * thwb : 0.f);
        td = wave_sum(td);
        const float z  = td + thbv;
        const float th = alphav / (1.0f + expf(-z));

        const float ga  = fmaxf(ra - th, 0.f);
        const float gb_ = hb ? fmaxf(rb - th, 0.f) : 0.f;
        const float sg  = wave_sum(ga + gb_);
        const float wf  = 1.0f / (sg + EPSF);

        w2[l] = ga * wf * nrm[l];
        if (hb) w2[64 + l] = gb_ * wf * nrm[64 + l];
        if (l == 0) Wsh[0] = sg * wf;
    }
    __syncthreads();

    // ---------- Pass 3: shift[d] = sum_n w2[n]u[n][d], split + dual chains ----------
    {
        if (tid < 768) {
            const int h = (tid >= 384) ? 1 : 0;
            const int j = tid - (h ? 384 : 0);
            const unsigned int* up = u + h * 50 * 384 + j;
            const float* wp = w2 + h * 50;
            float ax0 = 0.f, ay0 = 0.f, ax1 = 0.f, ay1 = 0.f;
#pragma unroll 5
            for (int n = 0; n < 50; n += 2) {
                const float wv0 = wp[n];
                const float wv1 = wp[n + 1];
                const unsigned int pw0 = up[n * 384];
                const unsigned int pw1 = up[(n + 1) * 384];
                ax0 = fmaf(wv0, bflo(pw0), ax0); ay0 = fmaf(wv0, bfhi(pw0), ay0);
                ax1 = fmaf(wv1, bflo(pw1), ax1); ay1 = fmaf(wv1, bfhi(pw1), ay1);
            }
            float* dst = h ? S : P;          // S is dead after pass 2a
            *(float2*)&dst[2 * j] = make_float2(ax0 + ax1, ay0 + ay1);
        }
        __syncthreads();
        if (tid < 384) {
            const float2 a = *(float2*)&S[2 * tid];
            const float2 p = *(float2*)&P[2 * tid];
            const float W = Wsh[0];
            float2 o;
            o.x = ccv.x + ((a.x + p.x) - ccv.x * W) * (1.0f / NROW);
            o.y = ccv.y + ((a.y + p.y) - ccv.y * W) * (1.0f / NROW);
            *(float2*)(out + (size_t)b * DDIM + 2 * tid) = o;
        }
    }
}

extern "C" void kernel_launch(void* const* d_in, const int* in_sizes, int n_in,
                              void* d_out, int out_size, void* d_ws, size_t ws_size,
                              hipStream_t stream) {
    const float* x     = (const float*)d_in[0];
    const float* cc    = (const float*)d_in[1];
    const float* alpha = (const float*)d_in[2];
    const float* gamma = (const float*)d_in[3];
    const float* beta  = (const float*)d_in[4];
    const float* thw   = (const float*)d_in[5];
    const float* thb   = (const float*)d_in[6];
    float* out = (float*)d_out;

    ccs_kernel<<<1024, BT, LDS_BYTES, stream>>>(x, cc, alpha, gamma, beta, thw, thb, out);
}